// Round 12
// baseline (219.410 us; speedup 1.0000x reference)
//
#include <hip/hip_runtime.h>
#include <hip/hip_bf16.h>

#define N_NODES 50000
#define NPAD 50048      // padded to 64-node blocks; rows >= N_NODES are zero
#define ZROW N_NODES    // index of a guaranteed-zero row (padding target)
#define D0 128
#define D1 256
#define D2 128
#define N4 1600000      // N_NODES*D0/4 float4s
#define NB4 1601536     // NPAD*D0/4 ushort4s (x_bf element groups incl. pad rows)
#define CAP 128         // per-node bucket capacity (Poisson(12.8): max deg ~40)

typedef __attribute__((ext_vector_type(8))) short short8;
typedef __attribute__((ext_vector_type(8))) unsigned short ushort8;
typedef __attribute__((ext_vector_type(4))) float f32x4;

static __device__ __forceinline__ unsigned short f2bf(float f) {
    __hip_bfloat16 h = __float2bfloat16(f);
    return *(unsigned short*)&h;
}
static __device__ __forceinline__ float bf2f(unsigned short u) {
    return __uint_as_float(((unsigned int)u) << 16);
}

// ---------------- prep (fused): x->bf16 (+zero pad rows), cursor zero, weight pack, int64 detect ----------------
__global__ __launch_bounds__(256) void k_prep(const float* __restrict__ x,
                                              unsigned short* __restrict__ x_bf,
                                              int* __restrict__ cursor,
                                              const float* __restrict__ W1,
                                              const float* __restrict__ W2,
                                              unsigned short* __restrict__ W1p,
                                              unsigned short* __restrict__ W2p,
                                              const int* __restrict__ ei32,
                                              int* __restrict__ flag) {
    int idx = blockIdx.x * 256 + threadIdx.x;
    if (idx < N4) {
        float4 v = ((const float4*)x)[idx];
        ushort4 u;
        u.x = f2bf(v.x); u.y = f2bf(v.y); u.z = f2bf(v.z); u.w = f2bf(v.w);
        ((ushort4*)x_bf)[idx] = u;
    } else if (idx < NB4) {
        ushort4 z = {0, 0, 0, 0};
        ((ushort4*)x_bf)[idx] = z;   // zero pad rows (ZROW lives here)
    }
    if (idx < N_NODES) cursor[idx] = 0;
    if (idx < 2 * D0 * D1) {  // weight pack into MFMA B-frag order
        if (idx < D0 * D1) {
            int j = idx & 7, lane = (idx >> 3) & 63, tile = idx >> 9;
            int ct = tile & 15, kt = tile >> 4;
            int k = kt * 32 + (lane >> 4) * 8 + j;
            int n = ct * 16 + (lane & 15);
            W1p[idx] = f2bf(W1[n * D0 + k]);
        } else {
            int i2 = idx - D0 * D1;
            int j = i2 & 7, lane = (i2 >> 3) & 63, tile = i2 >> 9;
            int ct = tile & 7, kt = tile >> 3;
            int k = kt * 32 + (lane >> 4) * 8 + j;
            int n = ct * 16 + (lane & 15);
            W2p[i2] = f2bf(W2[n * D1 + k]);
        }
    }
    if (blockIdx.x == gridDim.x - 1 && threadIdx.x < 64) {
        int lane = threadIdx.x;
        int nz = 0;
#pragma unroll
        for (int k = 0; k < 16; k++) nz += (ei32[2 * (lane * 16 + k) + 1] != 0);
#pragma unroll
        for (int off = 32; off > 0; off >>= 1) nz += __shfl_down(nz, off, 64);
        if (lane == 0) *flag = (nz == 0) ? 1 : 0;  // 1 => int64 layout
    }
}

// ---------------- bucket edges into fixed-capacity CSR; 2 edges/thread ----------------
__global__ __launch_bounds__(256) void k_bucket(const int* __restrict__ ei,
                                                int* __restrict__ cursor,
                                                int* __restrict__ csr, int E,
                                                const int* __restrict__ flag) {
    int i = blockIdx.x * 256 + threadIdx.x;
    if (2 * i >= E) return;
    int is64 = *flag;
    int s0, d0, s1, d1;
    if (is64) {
        int4 sp = ((const int4*)ei)[i];
        int4 dp = ((const int4*)(ei + 2 * (size_t)E))[i];
        s0 = sp.x; s1 = sp.z; d0 = dp.x; d1 = dp.z;
    } else {
        int2 sp = ((const int2*)ei)[i];
        int2 dp = ((const int2*)(ei + (size_t)E))[i];
        s0 = sp.x; s1 = sp.y; d0 = dp.x; d1 = dp.y;
    }
    int p0 = atomicAdd(&cursor[d0], 1);
    if (p0 < CAP) csr[(size_t)d0 * CAP + p0] = s0;
    if (2 * i + 1 < E) {
        int p1 = atomicAdd(&cursor[d1], 1);
        if (p1 < CAP) csr[(size_t)d1 * CAP + p1] = s1;
    }
}

// ---------------- gather1: a_bf[n] = bf16((x[n]+sum x[src])*invd)
// 16 lanes/node (ushort8/lane), 16 nodes/block, 8-deep pipeline ----------------
__global__ __launch_bounds__(256) void k_gather(const unsigned short* __restrict__ x_bf,
                                                const int* __restrict__ csr,
                                                const int* __restrict__ cursor,
                                                unsigned short* __restrict__ a_bf) {
    int tid = threadIdx.x;
    int h = tid & 15;
    int node = blockIdx.x * 16 + (tid >> 4);
    unsigned short* dstp = a_bf + (size_t)node * 128 + h * 8;
    if (node >= N_NODES) {
        ushort8 z = {0, 0, 0, 0, 0, 0, 0, 0};
        *(ushort8*)dstp = z;
        return;
    }
    float a0[8], a1[8];
    ushort8 u = *(const ushort8*)(x_bf + (size_t)node * 128 + h * 8);  // self loop
#pragma unroll
    for (int t = 0; t < 8; t++) { a0[t] = bf2f(u[t]); a1[t] = 0.f; }
    int dg = cursor[node]; if (dg > CAP) dg = CAP;
    const int* cp = csr + (size_t)node * CAP;
    int jn = (dg + 7) & ~7;
    for (int j = 0; j < jn; j += 8) {
        int idx[8];
#pragma unroll
        for (int u8 = 0; u8 < 8; u8++) {
            int jj = j + u8;
            idx[u8] = (jj < dg) ? cp[jj] : ZROW;  // ZROW is all-zero
        }
        ushort8 rr[8];
#pragma unroll
        for (int u8 = 0; u8 < 8; u8++)
            rr[u8] = *(const ushort8*)(x_bf + (size_t)idx[u8] * 128 + h * 8);
#pragma unroll
        for (int t = 0; t < 8; t++) {
            a0[t] += bf2f(rr[0][t]) + bf2f(rr[2][t]) + bf2f(rr[4][t]) + bf2f(rr[6][t]);
            a1[t] += bf2f(rr[1][t]) + bf2f(rr[3][t]) + bf2f(rr[5][t]) + bf2f(rr[7][t]);
        }
    }
    float invd = 1.0f / (float)(dg + 1);
    ushort8 o;
#pragma unroll
    for (int t = 0; t < 8; t++) o[t] = f2bf((a0[t] + a1[t]) * invd);
    *(ushort8*)dstp = o;
}

// ---------------- MFMA MLP: 64 nodes/block, 4 waves, wave-local, aliased LDS ----------------
#define H_LD 260   // stride in ushorts; 2-way-max bank conflicts (free)
__global__ __launch_bounds__(256, 4) void k_mlp(const unsigned short* __restrict__ a_bf,
                                                const unsigned short* __restrict__ W1p,
                                                const float* __restrict__ b1,
                                                const unsigned short* __restrict__ W2p,
                                                unsigned short* __restrict__ t_bf) {
    __shared__ unsigned short sbuf[4][16 * H_LD];  // 33.3 KB total
    int tid = threadIdx.x;
    int n0 = blockIdx.x * 64;
    int w = tid >> 6, lane = tid & 63;
    int m = lane & 15, q = lane >> 4;
    unsigned short* wbuf = sbuf[w];

    {   // stage A: wave-local; thread covers 32 ushorts of row lrow = lane>>2
        int lrow = lane >> 2;        // 0..15
        int quarter = lane & 3;      // 0..3
        const unsigned short* g = a_bf + (size_t)(n0 + w * 16 + lrow) * 128 + quarter * 32;
        unsigned short* l = wbuf + lrow * H_LD + quarter * 32;
        *(short8*)(l + 0)  = *(const short8*)(g + 0);
        *(short8*)(l + 8)  = *(const short8*)(g + 8);
        *(short8*)(l + 16) = *(const short8*)(g + 16);
        *(short8*)(l + 24) = *(const short8*)(g + 24);
    }
    // wave-local: no barrier needed

    {   // layer 1: af regs <- A (A region then dead); h = relu(a@W1^T+b1) overwrites buffer
        short8 af[4];
        const unsigned short* arow = wbuf + m * H_LD + q * 8;
#pragma unroll
        for (int kt = 0; kt < 4; kt++) af[kt] = *(const short8*)(arow + kt * 32);
#pragma unroll
        for (int ct = 0; ct < 16; ct++) {
            f32x4 acc = {0.f, 0.f, 0.f, 0.f};
#pragma unroll
            for (int kt = 0; kt < 4; kt++) {
                short8 bf = *(const short8*)(W1p + (((kt * 16 + ct) * 64 + lane) << 3));
                acc = __builtin_amdgcn_mfma_f32_16x16x32_bf16(af[kt], bf, acc, 0, 0, 0);
            }
            int c = ct * 16 + m;
            float bias = b1[c];
#pragma unroll
            for (int r = 0; r < 4; r++) {
                float v = fmaxf(acc[r] + bias, 0.0f);
                wbuf[(q * 4 + r) * H_LD + c] = f2bf(v);
            }
        }
    }

    {   // layer 2: t = h @ W2^T
        short8 hf[8];
        const unsigned short* hrow = wbuf + m * H_LD + q * 8;
#pragma unroll
        for (int kt = 0; kt < 8; kt++) hf[kt] = *(const short8*)(hrow + kt * 32);
#pragma unroll
        for (int ct = 0; ct < 8; ct++) {
            f32x4 acc = {0.f, 0.f, 0.f, 0.f};
#pragma unroll
            for (int kt = 0; kt < 8; kt++) {
                short8 bf = *(const short8*)(W2p + (((kt * 8 + ct) * 64 + lane) << 3));
                acc = __builtin_amdgcn_mfma_f32_16x16x32_bf16(hf[kt], bf, acc, 0, 0, 0);
            }
            int c = ct * 16 + m;
#pragma unroll
            for (int r = 0; r < 4; r++) {
                int node = n0 + w * 16 + q * 4 + r;
                t_bf[(size_t)node * 128 + c] = (node < N_NODES) ? f2bf(acc[r]) : (unsigned short)0;
            }
        }
    }
}

// ---------------- gather2 + epilogue; 16 lanes/node, 8-deep pipeline, 16 nodes/block ----------------
__global__ __launch_bounds__(256) void k_gather_final(const unsigned short* __restrict__ t,
                                                      const int* __restrict__ csr,
                                                      const int* __restrict__ cursor,
                                                      const float* __restrict__ b2,
                                                      const float* __restrict__ ls,
                                                      float* __restrict__ out) {
    int tid = threadIdx.x;
    int h = tid & 15;
    int node = blockIdx.x * 16 + (tid >> 4);

    float a0[8], a1[8];
    ushort8 u = *(const ushort8*)(t + (size_t)node * 128 + h * 8);  // self loop
#pragma unroll
    for (int k = 0; k < 8; k++) { a0[k] = bf2f(u[k]); a1[k] = 0.f; }
    int dg = cursor[node]; if (dg > CAP) dg = CAP;
    const int* cp = csr + (size_t)node * CAP;
    int jn = (dg + 7) & ~7;
    for (int j = 0; j < jn; j += 8) {
        int idx[8];
#pragma unroll
        for (int u8 = 0; u8 < 8; u8++) {
            int jj = j + u8;
            idx[u8] = (jj < dg) ? cp[jj] : ZROW;  // ZROW row of t is zero
        }
        ushort8 rr[8];
#pragma unroll
        for (int u8 = 0; u8 < 8; u8++)
            rr[u8] = *(const ushort8*)(t + (size_t)idx[u8] * 128 + h * 8);
#pragma unroll
        for (int k = 0; k < 8; k++) {
            a0[k] += bf2f(rr[0][k]) + bf2f(rr[2][k]) + bf2f(rr[4][k]) + bf2f(rr[6][k]);
            a1[k] += bf2f(rr[1][k]) + bf2f(rr[3][k]) + bf2f(rr[5][k]) + bf2f(rr[7][k]);
        }
    }
    float invd = 1.0f / (float)(dg + 1);
    float4 bb0 = ((const float4*)b2)[h * 2];
    float4 bb1 = ((const float4*)b2)[h * 2 + 1];
    float v[8];
    v[0] = (a0[0] + a1[0]) * invd + bb0.x;
    v[1] = (a0[1] + a1[1]) * invd + bb0.y;
    v[2] = (a0[2] + a1[2]) * invd + bb0.z;
    v[3] = (a0[3] + a1[3]) * invd + bb0.w;
    v[4] = (a0[4] + a1[4]) * invd + bb1.x;
    v[5] = (a0[5] + a1[5]) * invd + bb1.y;
    v[6] = (a0[6] + a1[6]) * invd + bb1.z;
    v[7] = (a0[7] + a1[7]) * invd + bb1.w;

    float s = 0.f;
#pragma unroll
    for (int k = 0; k < 8; k++) s += v[k] * v[k];
#pragma unroll
    for (int msk = 8; msk > 0; msk >>= 1) s += __shfl_xor(s, msk, 64);  // within 16-lane group
    float nrm = fmaxf(sqrtf(s), 1e-12f);
    float scale = expf(ls[0]) / nrm;
    float4 o0, o1;
    o0.x = v[0] * scale; o0.y = v[1] * scale; o0.z = v[2] * scale; o0.w = v[3] * scale;
    o1.x = v[4] * scale; o1.y = v[5] * scale; o1.z = v[6] * scale; o1.w = v[7] * scale;
    float* op = out + (size_t)node * 128 + h * 8;
    *(float4*)(op + 0) = o0;
    *(float4*)(op + 4) = o1;
}

extern "C" void kernel_launch(void* const* d_in, const int* in_sizes, int n_in,
                              void* d_out, int out_size, void* d_ws, size_t ws_size,
                              hipStream_t stream) {
    const float* x  = (const float*)d_in[0];
    const int*   ei = (const int*)d_in[1];
    const float* W1 = (const float*)d_in[2];
    const float* b1 = (const float*)d_in[3];
    const float* W2 = (const float*)d_in[4];
    const float* b2 = (const float*)d_in[5];
    const float* ls = (const float*)d_in[6];
    float* out = (float*)d_out;

    const int E = in_sizes[1] / 2;  // 640000 edges

    // workspace layout (256B aligned), ~65 MB total
    char* ws = (char*)d_ws;
    size_t off = 0;
    auto alloc = [&](size_t bytes) {
        size_t o = off;
        off = (off + bytes + 255) & ~(size_t)255;
        return o;
    };
    int*            flag   = (int*)(ws + alloc(256));
    int*            cursor = (int*)(ws + alloc((size_t)N_NODES * 4));
    int*            csr    = (int*)(ws + alloc((size_t)N_NODES * CAP * 4));
    unsigned short* W1p    = (unsigned short*)(ws + alloc((size_t)D0 * D1 * 2));
    unsigned short* W2p    = (unsigned short*)(ws + alloc((size_t)D1 * D2 * 2));
    unsigned short* x_bf   = (unsigned short*)(ws + alloc((size_t)NPAD * D0 * 2));
    unsigned short* a_bf   = (unsigned short*)(ws + alloc((size_t)NPAD * D0 * 2));
    unsigned short* t_bf   = (unsigned short*)(ws + alloc((size_t)NPAD * D2 * 2));

    k_prep<<<(NB4 + 255) / 256, 256, 0, stream>>>(x, x_bf, cursor, W1, W2, W1p, W2p, ei, flag);
    k_bucket<<<(E / 2 + 255) / 256, 256, 0, stream>>>(ei, cursor, csr, E, flag);
    k_gather<<<NPAD / 16, 256, 0, stream>>>(x_bf, csr, cursor, a_bf);
    k_mlp<<<NPAD / 64, 256, 0, stream>>>(a_bf, W1p, b1, W2p, t_bf);
    k_gather_final<<<N_NODES / 16, 256, 0, stream>>>(t_bf, csr, cursor, b2, ls, out);
}

// Round 13
// 215.352 us; speedup vs baseline: 1.0188x; 1.0188x over previous
//
#include <hip/hip_runtime.h>
#include <hip/hip_bf16.h>

#define N_NODES 50000
#define NPAD 50048      // padded to 64-node blocks; rows >= N_NODES are zero
#define ZROW N_NODES    // index of a guaranteed-zero row (padding target)
#define D0 128
#define D1 256
#define D2 128
#define N4 1600000      // N_NODES*D0/4 float4s
#define NB4 1601536     // NPAD*D0/4 ushort4s (x_bf element groups incl. pad rows)
#define CAP 128         // per-node bucket capacity (Poisson(12.8): max deg ~40)

typedef __attribute__((ext_vector_type(8))) short short8;
typedef __attribute__((ext_vector_type(8))) unsigned short ushort8;
typedef __attribute__((ext_vector_type(4))) float f32x4;

static __device__ __forceinline__ unsigned short f2bf(float f) {
    __hip_bfloat16 h = __float2bfloat16(f);
    return *(unsigned short*)&h;
}
static __device__ __forceinline__ float bf2f(unsigned short u) {
    return __uint_as_float(((unsigned int)u) << 16);
}

// ---------------- prep (fused): x->bf16 (+zero pad rows), cursor zero, weight pack, int64 detect ----------------
__global__ __launch_bounds__(256) void k_prep(const float* __restrict__ x,
                                              unsigned short* __restrict__ x_bf,
                                              int* __restrict__ cursor,
                                              const float* __restrict__ W1,
                                              const float* __restrict__ W2,
                                              unsigned short* __restrict__ W1p,
                                              unsigned short* __restrict__ W2p,
                                              const int* __restrict__ ei32,
                                              int* __restrict__ flag) {
    int idx = blockIdx.x * 256 + threadIdx.x;
    if (idx < N4) {
        float4 v = ((const float4*)x)[idx];
        ushort4 u;
        u.x = f2bf(v.x); u.y = f2bf(v.y); u.z = f2bf(v.z); u.w = f2bf(v.w);
        ((ushort4*)x_bf)[idx] = u;
    } else if (idx < NB4) {
        ushort4 z = {0, 0, 0, 0};
        ((ushort4*)x_bf)[idx] = z;   // zero pad rows (ZROW lives here)
    }
    if (idx < N_NODES) cursor[idx] = 0;
    if (idx < 2 * D0 * D1) {  // weight pack into MFMA B-frag order
        if (idx < D0 * D1) {
            int j = idx & 7, lane = (idx >> 3) & 63, tile = idx >> 9;
            int ct = tile & 15, kt = tile >> 4;
            int k = kt * 32 + (lane >> 4) * 8 + j;
            int n = ct * 16 + (lane & 15);
            W1p[idx] = f2bf(W1[n * D0 + k]);
        } else {
            int i2 = idx - D0 * D1;
            int j = i2 & 7, lane = (i2 >> 3) & 63, tile = i2 >> 9;
            int ct = tile & 7, kt = tile >> 3;
            int k = kt * 32 + (lane >> 4) * 8 + j;
            int n = ct * 16 + (lane & 15);
            W2p[i2] = f2bf(W2[n * D1 + k]);
        }
    }
    if (blockIdx.x == gridDim.x - 1 && threadIdx.x < 64) {
        int lane = threadIdx.x;
        int nz = 0;
#pragma unroll
        for (int k = 0; k < 16; k++) nz += (ei32[2 * (lane * 16 + k) + 1] != 0);
#pragma unroll
        for (int off = 32; off > 0; off >>= 1) nz += __shfl_down(nz, off, 64);
        if (lane == 0) *flag = (nz == 0) ? 1 : 0;  // 1 => int64 layout
    }
}

// ---------------- bucket edges into fixed-capacity CSR; 2 edges/thread ----------------
__global__ __launch_bounds__(256) void k_bucket(const int* __restrict__ ei,
                                                int* __restrict__ cursor,
                                                int* __restrict__ csr, int E,
                                                const int* __restrict__ flag) {
    int i = blockIdx.x * 256 + threadIdx.x;
    if (2 * i >= E) return;
    int is64 = *flag;
    int s0, d0, s1, d1;
    if (is64) {
        int4 sp = ((const int4*)ei)[i];
        int4 dp = ((const int4*)(ei + 2 * (size_t)E))[i];
        s0 = sp.x; s1 = sp.z; d0 = dp.x; d1 = dp.z;
    } else {
        int2 sp = ((const int2*)ei)[i];
        int2 dp = ((const int2*)(ei + (size_t)E))[i];
        s0 = sp.x; s1 = sp.y; d0 = dp.x; d1 = dp.y;
    }
    int p0 = atomicAdd(&cursor[d0], 1);
    if (p0 < CAP) csr[(size_t)d0 * CAP + p0] = s0;
    if (2 * i + 1 < E) {
        int p1 = atomicAdd(&cursor[d1], 1);
        if (p1 < CAP) csr[(size_t)d1 * CAP + p1] = s1;
    }
}

// ---------------- gather1: wave-per-node. lane = (slot s=lane>>4, chan-group h=lane&15)
// per trip: 8 edges (2 unrolled granules of 4); slot-combine via shfl_xor(16,32) ----------------
__global__ __launch_bounds__(256) void k_gather(const unsigned short* __restrict__ x_bf,
                                                const int* __restrict__ csr,
                                                const int* __restrict__ cursor,
                                                unsigned short* __restrict__ a_bf) {
    int lane = threadIdx.x & 63;
    int node = blockIdx.x * 4 + (threadIdx.x >> 6);
    int s = lane >> 4, h = lane & 15;

    if (node >= N_NODES) {
        if (s == 0) {
            ushort8 z = {0, 0, 0, 0, 0, 0, 0, 0};
            *(ushort8*)(a_bf + (size_t)node * 128 + h * 8) = z;
        }
        return;
    }
    float a[8];
    {   // self loop: slot 0 only
        ushort8 su = *(const ushort8*)(x_bf + (size_t)node * 128 + h * 8);
#pragma unroll
        for (int k = 0; k < 8; k++) a[k] = (s == 0) ? bf2f(su[k]) : 0.f;
    }
    int dg = cursor[node]; if (dg > CAP) dg = CAP;
    const int* cp = csr + (size_t)node * CAP;
    int jn = (dg + 7) & ~7;
    for (int j = 0; j < jn; j += 8) {
        int j0 = j + s, j1 = j + 4 + s;
        int i0 = (j0 < dg) ? cp[j0] : ZROW;
        int i1 = (j1 < dg) ? cp[j1] : ZROW;
        ushort8 r0 = *(const ushort8*)(x_bf + (size_t)i0 * 128 + h * 8);
        ushort8 r1 = *(const ushort8*)(x_bf + (size_t)i1 * 128 + h * 8);
#pragma unroll
        for (int k = 0; k < 8; k++) a[k] += bf2f(r0[k]) + bf2f(r1[k]);
    }
    // combine the 4 edge-slots
#pragma unroll
    for (int k = 0; k < 8; k++) {
        a[k] += __shfl_xor(a[k], 16, 64);
        a[k] += __shfl_xor(a[k], 32, 64);
    }
    if (s == 0) {
        float invd = 1.0f / (float)(dg + 1);
        ushort8 o;
#pragma unroll
        for (int k = 0; k < 8; k++) o[k] = f2bf(a[k] * invd);
        *(ushort8*)(a_bf + (size_t)node * 128 + h * 8) = o;
    }
}

// ---------------- MFMA MLP: 64 nodes/block, 4 waves, wave-local, aliased LDS ----------------
#define H_LD 260   // stride in ushorts; 2-way-max bank conflicts (free)
__global__ __launch_bounds__(256, 4) void k_mlp(const unsigned short* __restrict__ a_bf,
                                                const unsigned short* __restrict__ W1p,
                                                const float* __restrict__ b1,
                                                const unsigned short* __restrict__ W2p,
                                                unsigned short* __restrict__ t_bf) {
    __shared__ unsigned short sbuf[4][16 * H_LD];  // 33.3 KB total
    int tid = threadIdx.x;
    int n0 = blockIdx.x * 64;
    int w = tid >> 6, lane = tid & 63;
    int m = lane & 15, q = lane >> 4;
    unsigned short* wbuf = sbuf[w];

    {   // stage A: wave-local
        int lrow = lane >> 2;
        int quarter = lane & 3;
        const unsigned short* g = a_bf + (size_t)(n0 + w * 16 + lrow) * 128 + quarter * 32;
        unsigned short* l = wbuf + lrow * H_LD + quarter * 32;
        *(short8*)(l + 0)  = *(const short8*)(g + 0);
        *(short8*)(l + 8)  = *(const short8*)(g + 8);
        *(short8*)(l + 16) = *(const short8*)(g + 16);
        *(short8*)(l + 24) = *(const short8*)(g + 24);
    }

    {   // layer 1: af regs <- A (A region then dead); h overwrites buffer
        short8 af[4];
        const unsigned short* arow = wbuf + m * H_LD + q * 8;
#pragma unroll
        for (int kt = 0; kt < 4; kt++) af[kt] = *(const short8*)(arow + kt * 32);
#pragma unroll
        for (int ct = 0; ct < 16; ct++) {
            f32x4 acc = {0.f, 0.f, 0.f, 0.f};
#pragma unroll
            for (int kt = 0; kt < 4; kt++) {
                short8 bf = *(const short8*)(W1p + (((kt * 16 + ct) * 64 + lane) << 3));
                acc = __builtin_amdgcn_mfma_f32_16x16x32_bf16(af[kt], bf, acc, 0, 0, 0);
            }
            int c = ct * 16 + m;
            float bias = b1[c];
#pragma unroll
            for (int r = 0; r < 4; r++) {
                float v = fmaxf(acc[r] + bias, 0.0f);
                wbuf[(q * 4 + r) * H_LD + c] = f2bf(v);
            }
        }
    }

    {   // layer 2: t = h @ W2^T
        short8 hf[8];
        const unsigned short* hrow = wbuf + m * H_LD + q * 8;
#pragma unroll
        for (int kt = 0; kt < 8; kt++) hf[kt] = *(const short8*)(hrow + kt * 32);
#pragma unroll
        for (int ct = 0; ct < 8; ct++) {
            f32x4 acc = {0.f, 0.f, 0.f, 0.f};
#pragma unroll
            for (int kt = 0; kt < 8; kt++) {
                short8 bf = *(const short8*)(W2p + (((kt * 8 + ct) * 64 + lane) << 3));
                acc = __builtin_amdgcn_mfma_f32_16x16x32_bf16(hf[kt], bf, acc, 0, 0, 0);
            }
            int c = ct * 16 + m;
#pragma unroll
            for (int r = 0; r < 4; r++) {
                int node = n0 + w * 16 + q * 4 + r;
                t_bf[(size_t)node * 128 + c] = (node < N_NODES) ? f2bf(acc[r]) : (unsigned short)0;
            }
        }
    }
}

// ---------------- gather2 + epilogue: wave-per-node, same slot layout; norm via xor-butterfly ----------------
__global__ __launch_bounds__(256) void k_gather_final(const unsigned short* __restrict__ t,
                                                      const int* __restrict__ csr,
                                                      const int* __restrict__ cursor,
                                                      const float* __restrict__ b2,
                                                      const float* __restrict__ ls,
                                                      float* __restrict__ out) {
    int lane = threadIdx.x & 63;
    int node = blockIdx.x * 4 + (threadIdx.x >> 6);  // grid covers exactly N_NODES/4
    int s = lane >> 4, h = lane & 15;

    float a[8];
    {   // self loop: slot 0 only
        ushort8 su = *(const ushort8*)(t + (size_t)node * 128 + h * 8);
#pragma unroll
        for (int k = 0; k < 8; k++) a[k] = (s == 0) ? bf2f(su[k]) : 0.f;
    }
    int dg = cursor[node]; if (dg > CAP) dg = CAP;
    const int* cp = csr + (size_t)node * CAP;
    int jn = (dg + 7) & ~7;
    for (int j = 0; j < jn; j += 8) {
        int j0 = j + s, j1 = j + 4 + s;
        int i0 = (j0 < dg) ? cp[j0] : ZROW;
        int i1 = (j1 < dg) ? cp[j1] : ZROW;
        ushort8 r0 = *(const ushort8*)(t + (size_t)i0 * 128 + h * 8);
        ushort8 r1 = *(const ushort8*)(t + (size_t)i1 * 128 + h * 8);
#pragma unroll
        for (int k = 0; k < 8; k++) a[k] += bf2f(r0[k]) + bf2f(r1[k]);
    }
#pragma unroll
    for (int k = 0; k < 8; k++) {
        a[k] += __shfl_xor(a[k], 16, 64);
        a[k] += __shfl_xor(a[k], 32, 64);
    }
    float invd = 1.0f / (float)(dg + 1);
    float4 bb0 = ((const float4*)b2)[h * 2];
    float4 bb1 = ((const float4*)b2)[h * 2 + 1];
    float v[8];
    v[0] = a[0] * invd + bb0.x;
    v[1] = a[1] * invd + bb0.y;
    v[2] = a[2] * invd + bb0.z;
    v[3] = a[3] * invd + bb0.w;
    v[4] = a[4] * invd + bb1.x;
    v[5] = a[5] * invd + bb1.y;
    v[6] = a[6] * invd + bb1.z;
    v[7] = a[7] * invd + bb1.w;

    float sq = 0.f;
#pragma unroll
    for (int k = 0; k < 8; k++) sq += v[k] * v[k];
#pragma unroll
    for (int msk = 8; msk > 0; msk >>= 1) sq += __shfl_xor(sq, msk, 64);  // over the 16 chan-groups
    float nrm = fmaxf(sqrtf(sq), 1e-12f);
    float scale = expf(ls[0]) / nrm;
    if (s == 0) {
        float4 o0, o1;
        o0.x = v[0] * scale; o0.y = v[1] * scale; o0.z = v[2] * scale; o0.w = v[3] * scale;
        o1.x = v[4] * scale; o1.y = v[5] * scale; o1.z = v[6] * scale; o1.w = v[7] * scale;
        float* op = out + (size_t)node * 128 + h * 8;
        *(float4*)(op + 0) = o0;
        *(float4*)(op + 4) = o1;
    }
}

extern "C" void kernel_launch(void* const* d_in, const int* in_sizes, int n_in,
                              void* d_out, int out_size, void* d_ws, size_t ws_size,
                              hipStream_t stream) {
    const float* x  = (const float*)d_in[0];
    const int*   ei = (const int*)d_in[1];
    const float* W1 = (const float*)d_in[2];
    const float* b1 = (const float*)d_in[3];
    const float* W2 = (const float*)d_in[4];
    const float* b2 = (const float*)d_in[5];
    const float* ls = (const float*)d_in[6];
    float* out = (float*)d_out;

    const int E = in_sizes[1] / 2;  // 640000 edges

    // workspace layout (256B aligned), ~65 MB total
    char* ws = (char*)d_ws;
    size_t off = 0;
    auto alloc = [&](size_t bytes) {
        size_t o = off;
        off = (off + bytes + 255) & ~(size_t)255;
        return o;
    };
    int*            flag   = (int*)(ws + alloc(256));
    int*            cursor = (int*)(ws + alloc((size_t)N_NODES * 4));
    int*            csr    = (int*)(ws + alloc((size_t)N_NODES * CAP * 4));
    unsigned short* W1p    = (unsigned short*)(ws + alloc((size_t)D0 * D1 * 2));
    unsigned short* W2p    = (unsigned short*)(ws + alloc((size_t)D1 * D2 * 2));
    unsigned short* x_bf   = (unsigned short*)(ws + alloc((size_t)NPAD * D0 * 2));
    unsigned short* a_bf   = (unsigned short*)(ws + alloc((size_t)NPAD * D0 * 2));
    unsigned short* t_bf   = (unsigned short*)(ws + alloc((size_t)NPAD * D2 * 2));

    k_prep<<<(NB4 + 255) / 256, 256, 0, stream>>>(x, x_bf, cursor, W1, W2, W1p, W2p, ei, flag);
    k_bucket<<<(E / 2 + 255) / 256, 256, 0, stream>>>(ei, cursor, csr, E, flag);
    k_gather<<<NPAD / 4, 256, 0, stream>>>(x_bf, csr, cursor, a_bf);
    k_mlp<<<NPAD / 64, 256, 0, stream>>>(a_bf, W1p, b1, W2p, t_bf);
    k_gather_final<<<N_NODES / 4, 256, 0, stream>>>(t_bf, csr, cursor, b2, ls, out);
}